// Round 5
// baseline (1513.836 us; speedup 1.0000x reference)
//
#include <hip/hip_runtime.h>
#include <cmath>

typedef unsigned short u16;
typedef unsigned int u32;
typedef __attribute__((ext_vector_type(8))) short short8;   // 8 x bf16 (4 VGPRs)
typedef __attribute__((ext_vector_type(4))) short short4v;  // 4 x bf16
typedef __attribute__((ext_vector_type(4))) float f32x4;

__device__ __forceinline__ float bf2f(u16 h) {
  union { u32 u; float f; } v; v.u = ((u32)h) << 16; return v.f;
}
__device__ __forceinline__ u16 f2bf(float f) {
  union { float f; u32 u; } v; v.f = f;
  u32 u = v.u;
  u32 r = (u + 0x7FFFu + ((u >> 16) & 1u)) >> 16;   // RNE
  return (u16)r;
}

// ---------------------------------------------------------------- conversions
__global__ void convx_kernel(const float* __restrict__ x, u16* __restrict__ A0) {
  int idx = blockIdx.x * 256 + threadIdx.x;   // short4 slot
  int r = blockIdx.y;
  if (idx >= 752) return;
  short4v o;
  if (r < 40000 && idx < 750) {
    float4 v = *(const float4*)(x + (size_t)r * 3000 + idx * 4);
    o[0] = (short)f2bf(v.x); o[1] = (short)f2bf(v.y);
    o[2] = (short)f2bf(v.z); o[3] = (short)f2bf(v.w);
  } else {
    o[0] = 0; o[1] = 0; o[2] = 0; o[3] = 0;
  }
  *(short4v*)(A0 + (size_t)r * 3008 + idx * 4) = o;
}

__global__ void convw_kernel(const float* __restrict__ W, u16* __restrict__ Wt,
                             int K, int N, int Kp) {
  int k = blockIdx.x * 256 + threadIdx.x;
  int n = blockIdx.y;
  if (k >= Kp) return;
  float v = (k < K && n < N) ? W[(size_t)k * N + n] : 0.f;
  Wt[(size_t)n * Kp + k] = f2bf(v);
}

// ---------------------------------------------------------------- CSR build
__global__ void zero_kernel(int* p, int n) {
  int i = blockIdx.x * 256 + threadIdx.x;
  if (i < n) p[i] = 0;
}
__global__ void count_kernel(const int* __restrict__ rows, int* __restrict__ counts, int E) {
  int i = blockIdx.x * 256 + threadIdx.x;
  if (i < E) atomicAdd(&counts[rows[i]], 1);
}
__global__ __launch_bounds__(1024) void scan_kernel(const int* __restrict__ counts,
                                                    int* __restrict__ rowptr,
                                                    int* __restrict__ cursor, int n) {
  __shared__ int buf[1024];
  __shared__ int carry_s;
  int tid = threadIdx.x;
  if (tid == 0) carry_s = 0;
  __syncthreads();
  for (int base = 0; base < n; base += 1024) {
    int i = base + tid;
    int v = (i < n) ? counts[i] : 0;
    buf[tid] = v;
    __syncthreads();
    for (int off = 1; off < 1024; off <<= 1) {
      int tv = (tid >= off) ? buf[tid - off] : 0;
      __syncthreads();
      buf[tid] += tv;
      __syncthreads();
    }
    int incl = buf[tid];
    int carry = carry_s;
    if (i < n) { int ex = carry + incl - v; rowptr[i] = ex; cursor[i] = ex; }
    __syncthreads();
    if (tid == 1023) carry_s = carry + incl;
    __syncthreads();
  }
  if (tid == 0) rowptr[n] = carry_s;
}
__global__ void scatter_kernel(const int* __restrict__ rows, const int* __restrict__ cols,
                               const float* __restrict__ vals, int* __restrict__ cursor,
                               int* __restrict__ cols_s, float* __restrict__ vals_s, int E) {
  int i = blockIdx.x * 256 + threadIdx.x;
  if (i < E) {
    int r = rows[i];
    int p = atomicAdd(&cursor[r], 1);
    cols_s[p] = cols[i];
    vals_s[p] = vals[i];
  }
}

// ---------------------------------------------------------------- 128x128 bf16 GEMM (small layers)
#define BM 128
#define BN 128
#define BK 32

template <bool BIAS, bool RELU, bool OUTBF16, int CH>
__global__ __launch_bounds__(256, 2) void gemm_bf16(
    const u16* __restrict__ A, int lda, const u16* __restrict__ Bt, int ldb,
    void* __restrict__ C1, int ldc,
    const float* __restrict__ bias, int M, int Nreal, int K, int MT, int NT) {
  __shared__ __align__(16) u16 As[2][BM * BK];
  __shared__ __align__(16) u16 Bs[2][BN * BK];
  const int lin = blockIdx.x;
  const int per = CH * NT;
  const int g = lin / per;
  const int r0 = lin - g * per;
  const int bx0 = g * CH;
  const int cw = min(CH, MT - bx0);
  const int bx = bx0 + r0 % cw;
  const int by = r0 / cw;

  const int tid = threadIdx.x;
  const int lane = tid & 63;
  const int wave = tid >> 6;
  const int mblk = bx * BM;
  const int nblk = by * BN;
  const int wm = (wave & 1) * 64;
  const int wn = (wave >> 1) * 64;
  const int ml = lane & 15;
  const int kg = lane >> 4;

  f32x4 acc[4][4];
#pragma unroll
  for (int i = 0; i < 4; ++i)
#pragma unroll
    for (int j = 0; j < 4; ++j) acc[i][j] = (f32x4)(0.f);

  const int nk = K / BK;
  const int sr = tid >> 2;
  const int sc = (tid & 3) * 8;
  const u16* gA0 = A + (size_t)(mblk + sr) * lda + sc;
  const u16* gA1 = A + (size_t)(mblk + sr + 64) * lda + sc;
  const u16* gB0 = Bt + (size_t)(nblk + sr) * ldb + sc;
  const u16* gB1 = Bt + (size_t)(nblk + sr + 64) * ldb + sc;

  auto stage = [&](int buf, int kt) {
    const int ko = kt * BK;
    u16* lA = &As[buf][0] + wave * 512;
    u16* lB = &Bs[buf][0] + wave * 512;
    __builtin_amdgcn_global_load_lds((const void*)(gA0 + ko), (void*)lA, 16, 0, 0);
    __builtin_amdgcn_global_load_lds((const void*)(gA1 + ko), (void*)(lA + 2048), 16, 0, 0);
    __builtin_amdgcn_global_load_lds((const void*)(gB0 + ko), (void*)lB, 16, 0, 0);
    __builtin_amdgcn_global_load_lds((const void*)(gB1 + ko), (void*)(lB + 2048), 16, 0, 0);
  };

  stage(0, 0);
  asm volatile("s_waitcnt vmcnt(0)" ::: "memory");
  __syncthreads();

  int cur = 0;
  for (int kt = 0; kt < nk; ++kt) {
    if (kt + 1 < nk) stage(cur ^ 1, kt + 1);
    short8 af[4], bfr[4];
#pragma unroll
    for (int i = 0; i < 4; ++i) {
      af[i] = *(const short8*)&As[cur][(wm + i * 16 + ml) * BK + kg * 8];
      bfr[i] = *(const short8*)&Bs[cur][(wn + i * 16 + ml) * BK + kg * 8];
    }
#pragma unroll
    for (int i = 0; i < 4; ++i)
#pragma unroll
      for (int j = 0; j < 4; ++j)
        acc[i][j] = __builtin_amdgcn_mfma_f32_16x16x32_bf16(af[i], bfr[j], acc[i][j], 0, 0, 0);
    asm volatile("s_waitcnt vmcnt(0)" ::: "memory");
    __syncthreads();
    cur ^= 1;
  }

#pragma unroll
  for (int i = 0; i < 4; ++i) {
    const int row0 = mblk + wm + i * 16 + kg * 4;
#pragma unroll
    for (int j = 0; j < 4; ++j) {
      const int col = nblk + wn + j * 16 + ml;
      if (col < Nreal) {
        float bv = BIAS ? bias[col] : 0.f;
#pragma unroll
        for (int r = 0; r < 4; ++r) {
          const int row = row0 + r;
          if (row < M) {
            float v = acc[i][j][r] + bv;
            if (RELU) v = fmaxf(v, 0.f);
            if (OUTBF16)
              ((u16*)C1)[(size_t)row * ldc + col] = f2bf(v);
            else
              ((float*)C1)[(size_t)row * ldc + col] = v;
          }
        }
      }
    }
  }
}

// ---------------------------------------------------------------- 256x256 8-wave 4-phase GEMM
// BK=64, 2-deep LDS dbuf (128 KiB), chunk-XOR swizzle (measured: 0 bank conflicts),
// full-tile prefetch at q0 with counted vmcnt (never 0 in main loop), setprio on MFMA,
// XCD-grouped block mapping (NT same-panel blocks -> same XCD L2).
// SPLIT: cols<512 -> C1 (bias+relu), cols>=512 -> C2 (plain), both bf16, ldc=512.
template <bool BIAS, bool RELU, bool OUTBF16, bool SPLIT>
__global__ __launch_bounds__(512, 1) void gemm256(
    const u16* __restrict__ A, int lda, const u16* __restrict__ Bt, int ldb,
    void* __restrict__ C1, void* __restrict__ C2, int ldc,
    const float* __restrict__ bias, int M, int Nreal, int K, int MT2, int NT) {
  __shared__ __align__(16) u16 lds[2][2][256 * 64];
  const int tid = threadIdx.x;
  const int lane = tid & 63;
  const int wave = tid >> 6;
  const int wm = wave >> 2;        // 0..1
  const int wn = wave & 3;         // 0..3
  const int ml = lane & 15;
  const int kg = lane >> 4;

  // XCD-grouped mapping: ids in a group of 8*NT -> 8 A-panels; same-panel ids differ by 8
  const int grp = blockIdx.x / (8 * NT);
  const int rr = blockIdx.x % (8 * NT);
  const int nb = min(8, MT2 - grp * 8);
  const int bx = grp * 8 + rr % nb;
  const int by = rr / nb;
  const int mblk = bx * 256;
  const int nblk = by * 256;

  f32x4 acc[8][4];
#pragma unroll
  for (int i = 0; i < 8; ++i)
#pragma unroll
    for (int j = 0; j < 4; ++j) acc[i][j] = (f32x4)(0.f);

  // staging: one gload_lds per wave = 64 lanes x 16 B = 1 KB; 8 waves cover 64 rows.
  // LDS phys chunk c of row r holds logical chunk c ^ (r&7) (XOR involution, both sides).
  const int srow = tid >> 3;
  const int clog = (tid & 7) ^ (srow & 7);
  const size_t abase = (size_t)(mblk + srow) * lda + clog * 8;
  const size_t bbase = (size_t)(nblk + srow) * ldb + clog * 8;
  const int NKT = K / 64;

  auto stageA = [&](int d, int kt, int h) {
    u16* dst = &lds[d][0][0] + h * 4096 + wave * 512;
    const u16* src = A + abase + (size_t)h * 64 * lda + kt * 64;
    __builtin_amdgcn_global_load_lds((const void*)src, (void*)dst, 16, 0, 0);
  };
  auto stageB = [&](int d, int kt, int h) {
    u16* dst = &lds[d][1][0] + h * 4096 + wave * 512;
    const u16* src = Bt + bbase + (size_t)h * 64 * ldb + kt * 64;
    __builtin_amdgcn_global_load_lds((const void*)src, (void*)dst, 16, 0, 0);
  };
  // issue order per tile: B0,B1,B2,B3,A0,A2,A1,A3  (8 loads per wave)
  auto stageAll = [&](int d, int kt) {
    stageB(d, kt, 0); stageB(d, kt, 1); stageB(d, kt, 2); stageB(d, kt, 3);
    stageA(d, kt, 0); stageA(d, kt, 2); stageA(d, kt, 1); stageA(d, kt, 3);
  };
  auto readA = [&](int d, int im, int kk) -> short8 {
    const int r = wm * 128 + im * 16 + ml;
    const int ch = (kk * 4 + kg) ^ (r & 7);
    return *(const short8*)&lds[d][0][r * 64 + ch * 8];
  };
  auto readB = [&](int d, int j, int kk) -> short8 {
    const int r = wn * 64 + j * 16 + ml;
    const int ch = (kk * 4 + kg) ^ (r & 7);
    return *(const short8*)&lds[d][1][r * 64 + ch * 8];
  };

  // prologue: stage tile 0; retire B0-3,A0,A2 (keep A1,A3 in flight)
  stageAll(0, 0);
  asm volatile("s_waitcnt vmcnt(2)" ::: "memory");
  __builtin_amdgcn_s_barrier();

  for (int kt = 0; kt < NKT; ++kt) {
    const int d = kt & 1;
    const bool more = (kt + 1 < NKT);
    short8 bf2[4][2];
#pragma unroll
    for (int q = 0; q < 4; ++q) {
      if (q == 0) {
        // full-tile prefetch for kt+1 (8 loads; outstanding -> 10)
        if (more) stageAll(d ^ 1, kt + 1);
#pragma unroll
        for (int j = 0; j < 4; ++j) { bf2[j][0] = readB(d, j, 0); bf2[j][1] = readB(d, j, 1); }
      }
      // quadrant q: rows wm*128 + q*32 .. +31  (q0/q1 in h-group wm*2; q2/q3 in wm*2+1)
      short8 a00 = readA(d, 2 * q, 0);
      short8 a01 = readA(d, 2 * q, 1);
      short8 a10 = readA(d, 2 * q + 1, 0);
      short8 a11 = readA(d, 2 * q + 1, 1);
      __builtin_amdgcn_s_barrier();
      asm volatile("s_waitcnt lgkmcnt(0)" ::: "memory");
      __builtin_amdgcn_s_setprio(1);
#pragma unroll
      for (int j = 0; j < 4; ++j) {
        acc[2 * q][j]     = __builtin_amdgcn_mfma_f32_16x16x32_bf16(a00, bf2[j][0], acc[2 * q][j], 0, 0, 0);
        acc[2 * q + 1][j] = __builtin_amdgcn_mfma_f32_16x16x32_bf16(a10, bf2[j][0], acc[2 * q + 1][j], 0, 0, 0);
      }
#pragma unroll
      for (int j = 0; j < 4; ++j) {
        acc[2 * q][j]     = __builtin_amdgcn_mfma_f32_16x16x32_bf16(a01, bf2[j][1], acc[2 * q][j], 0, 0, 0);
        acc[2 * q + 1][j] = __builtin_amdgcn_mfma_f32_16x16x32_bf16(a11, bf2[j][1], acc[2 * q + 1][j], 0, 0, 0);
      }
      __builtin_amdgcn_s_setprio(0);
      // counted waits (ledger, per wave):
      //  q0-end: outstanding 10 -> vmcnt(8) retires THIS tile's A1,A3 (needed q2; issued
      //          at prev tile's q0, ~8 phases in flight). Last tile: vmcnt(0).
      //  q3-end: outstanding 8 -> vmcnt(2) retires NEXT tile's B0-3,A0,A2 (needed at
      //          next q0; issued this tile's q0, ~3.5 phases in flight). Keeps A1,A3.
      if (q == 0) {
        if (more) asm volatile("s_waitcnt vmcnt(8)" ::: "memory");
        else      asm volatile("s_waitcnt vmcnt(0)" ::: "memory");
      }
      if (q == 3 && more) asm volatile("s_waitcnt vmcnt(2)" ::: "memory");
      __builtin_amdgcn_s_barrier();
    }
  }

  // epilogue
  const int crow0 = mblk + wm * 128;
  const int ccol0 = nblk + wn * 64;
#pragma unroll
  for (int i = 0; i < 8; ++i) {
    const int row0 = crow0 + i * 16 + kg * 4;
#pragma unroll
    for (int j = 0; j < 4; ++j) {
      const int col = ccol0 + j * 16 + ml;
      if (SPLIT) {
        const bool second = (nblk >= 512);
        const float bv = second ? 0.f : bias[col];
#pragma unroll
        for (int r = 0; r < 4; ++r) {
          const int row = row0 + r;
          if (row < M) {
            float v = acc[i][j][r] + bv;
            if (!second) v = fmaxf(v, 0.f);
            u16* dst = second ? (u16*)C2 : (u16*)C1;
            dst[(size_t)row * 512 + (second ? col - 512 : col)] = f2bf(v);
          }
        }
      } else if (col < Nreal) {
        const float bv = BIAS ? bias[col] : 0.f;
#pragma unroll
        for (int r = 0; r < 4; ++r) {
          const int row = row0 + r;
          if (row < M) {
            float v = acc[i][j][r] + bv;
            if (RELU) v = fmaxf(v, 0.f);
            if (OUTBF16)
              ((u16*)C1)[(size_t)row * ldc + col] = f2bf(v);
            else
              ((float*)C1)[(size_t)row * ldc + col] = v;
          }
        }
      }
    }
  }
}

// ---------------------------------------------------------------- SpMM (CSR), vectorized
template <int D, bool RELU>
__global__ __launch_bounds__(256) void spmm_vec(const int* __restrict__ rowptr,
                                                const int* __restrict__ colidx,
                                                const float* __restrict__ vals,
                                                const u16* __restrict__ X,
                                                u16* __restrict__ Y) {
  constexpr int VE = D / 64;
  const int wave = threadIdx.x >> 6, lane = threadIdx.x & 63;
  const int row = blockIdx.x * 4 + wave;
  const int co = lane * VE;
  float acc[VE];
#pragma unroll
  for (int j = 0; j < VE; ++j) acc[j] = 0.f;
  const int s = rowptr[row], e = rowptr[row + 1];
  for (int i = s; i < e; ++i) {
    const int c = colidx[i];
    const float v = vals[i];
    const u16* xr = X + (size_t)c * D + co;
    if constexpr (VE == 8) {
      short8 x8 = *(const short8*)xr;
#pragma unroll
      for (int j = 0; j < 8; ++j) acc[j] += v * bf2f((u16)x8[j]);
    } else if constexpr (VE == 4) {
      short4v x4 = *(const short4v*)xr;
#pragma unroll
      for (int j = 0; j < 4; ++j) acc[j] += v * bf2f((u16)x4[j]);
    } else {
      u32 x2 = *(const u32*)xr;
      acc[0] += v * bf2f((u16)(x2 & 0xffffu));
      acc[1] += v * bf2f((u16)(x2 >> 16));
    }
  }
  u16* yr = Y + (size_t)row * D + co;
  if constexpr (VE == 8) {
    short8 o;
#pragma unroll
    for (int j = 0; j < 8; ++j) { float f = RELU ? fmaxf(acc[j], 0.f) : acc[j]; o[j] = (short)f2bf(f); }
    *(short8*)yr = o;
  } else if constexpr (VE == 4) {
    short4v o;
#pragma unroll
    for (int j = 0; j < 4; ++j) { float f = RELU ? fmaxf(acc[j], 0.f) : acc[j]; o[j] = (short)f2bf(f); }
    *(short4v*)yr = o;
  } else {
    float f0 = RELU ? fmaxf(acc[0], 0.f) : acc[0];
    float f1 = RELU ? fmaxf(acc[1], 0.f) : acc[1];
    *(u32*)yr = (u32)f2bf(f0) | ((u32)f2bf(f1) << 16);
  }
}

// final layer: D=20, fp32 out, no relu
__global__ __launch_bounds__(64) void spmm_out_kernel(const int* __restrict__ rowptr,
                                                      const int* __restrict__ colidx,
                                                      const float* __restrict__ vals,
                                                      const u16* __restrict__ X,
                                                      float* __restrict__ Y) {
  int row = blockIdx.x;
  int c = threadIdx.x;
  float acc = 0.f;
  int s = rowptr[row], e = rowptr[row + 1];
  for (int i = s; i < e; ++i) {
    int col = colidx[i];
    float v = vals[i];
    if (c < 20) acc += v * bf2f(X[(size_t)col * 20 + c]);
  }
  if (c < 20) Y[(size_t)row * 20 + c] = acc;
}

// ---------------------------------------------------------------- attention gate (vectorized)
template <int D>
__global__ __launch_bounds__(256) void attn_vec(const u16* __restrict__ h,
                                                const u16* __restrict__ t,
                                                const float* __restrict__ a,
                                                u16* __restrict__ emb) {
  constexpr int VE = D / 64;
  const int wave = threadIdx.x >> 6, lane = threadIdx.x & 63;
  const int row = blockIdx.x * 4 + wave;
  const int co = lane * VE;
  const u16* hr = h + (size_t)row * D + co;
  const u16* tr = t + (size_t)row * D + co;
  float hv[VE], tv[VE];
  if constexpr (VE == 8) {
    short8 h8 = *(const short8*)hr, t8 = *(const short8*)tr;
#pragma unroll
    for (int j = 0; j < 8; ++j) { hv[j] = bf2f((u16)h8[j]); tv[j] = bf2f((u16)t8[j]); }
  } else if constexpr (VE == 4) {
    short4v h4 = *(const short4v*)hr, t4 = *(const short4v*)tr;
#pragma unroll
    for (int j = 0; j < 4; ++j) { hv[j] = bf2f((u16)h4[j]); tv[j] = bf2f((u16)t4[j]); }
  } else {
    u32 h2 = *(const u32*)hr, t2 = *(const u32*)tr;
    hv[0] = bf2f((u16)(h2 & 0xffffu)); hv[1] = bf2f((u16)(h2 >> 16));
    tv[0] = bf2f((u16)(t2 & 0xffffu)); tv[1] = bf2f((u16)(t2 >> 16));
  }
  float wh = 0.f, wt = 0.f;
#pragma unroll
  for (int j = 0; j < VE; ++j) {
    float av = a[co + j];
    wh += av * hv[j];
    wt += av * tv[j];
  }
  for (int off = 32; off; off >>= 1) {
    wh += __shfl_xor(wh, off);
    wt += __shfl_xor(wt, off);
  }
  float m = fmaxf(wh, wt);
  float e1 = expf(wh - m), e2 = expf(wt - m);
  float inv = 1.f / (e1 + e2);
  float b1 = e1 * inv, b2 = e2 * inv;
  u16* er = emb + (size_t)row * D + co;
  if constexpr (VE == 8) {
    short8 o;
#pragma unroll
    for (int j = 0; j < 8; ++j) o[j] = (short)f2bf(b1 * hv[j] + b2 * tv[j]);
    *(short8*)er = o;
  } else if constexpr (VE == 4) {
    short4v o;
#pragma unroll
    for (int j = 0; j < 4; ++j) o[j] = (short)f2bf(b1 * hv[j] + b2 * tv[j]);
    *(short4v*)er = o;
  } else {
    *(u32*)er = (u32)f2bf(b1 * hv[0] + b2 * tv[0]) | ((u32)f2bf(b1 * hv[1] + b2 * tv[1]) << 16);
  }
}

// emb4[40000,128] @ W5[128,20] -> xw5 bf16 [40000,20]
__global__ __launch_bounds__(64) void xw5_kernel(const u16* __restrict__ emb,
                                                 const float* __restrict__ W5,
                                                 u16* __restrict__ xw5) {
  int row = blockIdx.x;
  int c = threadIdx.x;
  if (c >= 20) return;
  const short8* er = (const short8*)(emb + (size_t)row * 128);
  float acc = 0.f;
#pragma unroll
  for (int k8 = 0; k8 < 16; ++k8) {
    short8 v = er[k8];
#pragma unroll
    for (int j = 0; j < 8; ++j) acc += bf2f((u16)v[j]) * W5[(k8 * 8 + j) * 20 + c];
  }
  xw5[(size_t)row * 20 + c] = f2bf(acc);
}

__global__ void sig_exp_kernel(const float* __restrict__ scale, const float* __restrict__ additive,
                               float* __restrict__ osig, float* __restrict__ oexp, int g) {
  int i = blockIdx.x * 256 + threadIdx.x;
  if (i < g) {
    osig[i] = 1.f / (1.f + expf(-scale[i]));
    oexp[i] = expf(additive[i]);
  }
}

// ---------------------------------------------------------------- launch
extern "C" void kernel_launch(void* const* d_in, const int* in_sizes, int n_in,
                              void* d_out, int out_size, void* d_ws, size_t ws_size,
                              hipStream_t stream) {
  (void)n_in; (void)out_size; (void)ws_size;
  const float* x      = (const float*)d_in[0];
  const int*   arows  = (const int*)d_in[1];
  const int*   acols  = (const int*)d_in[2];
  const float* avals  = (const float*)d_in[3];
  const float* W1     = (const float*)d_in[4];
  const float* W2     = (const float*)d_in[5];
  const float* W3     = (const float*)d_in[6];
  const float* W4     = (const float*)d_in[7];
  const float* W5     = (const float*)d_in[8];
  const float* enc1_w = (const float*)d_in[9],  *enc1_b = (const float*)d_in[10];
  const float* enc2_w = (const float*)d_in[11], *enc2_b = (const float*)d_in[12];
  const float* enc3_w = (const float*)d_in[13], *enc3_b = (const float*)d_in[14];
  const float* zl_w   = (const float*)d_in[15], *zl_b   = (const float*)d_in[16];
  const float* dec1_w = (const float*)d_in[17], *dec1_b = (const float*)d_in[18];
  const float* dec2_w = (const float*)d_in[19], *dec2_b = (const float*)d_in[20];
  const float* dec3_w = (const float*)d_in[21], *dec3_b = (const float*)d_in[22];
  const float* xbar_w = (const float*)d_in[23], *xbar_b = (const float*)d_in[24];
  const float* a1 = (const float*)d_in[25], *a2 = (const float*)d_in[26];
  const float* a3 = (const float*)d_in[27], *a4 = (const float*)d_in[28];
  const float* scale = (const float*)d_in[29], *additive = (const float*)d_in[30];

  const int E = in_sizes[1];
  const int N = 40000, G = 3000, Kx = 3008;
  const int Mp = 40192;          // 157 * 256

  float* out      = (float*)d_out;
  float* out_gcn  = out;                                   // [40000,20]
  float* out_xbar = out + (size_t)N * 20;                  // [40000,3000]
  float* out_sig  = out_xbar + (size_t)N * G;              // [3000]
  float* out_exp  = out_sig + G;                           // [3000]

  char* wsb = (char*)d_ws;
  size_t off = 0;
  auto alloc = [&](size_t b) -> void* {
    void* p = wsb + off;
    off = (off + b + 255) & ~(size_t)255;
    return p;
  };
  u16* A0    = (u16*)alloc((size_t)Mp * Kx * 2);
  u16* t1    = (u16*)alloc((size_t)Mp * 512 * 2);
  u16* t2    = (u16*)alloc((size_t)Mp * 256 * 2);
  u16* t3    = (u16*)alloc((size_t)Mp * 128 * 2);
  u16* zb    = (u16*)alloc((size_t)Mp * 128 * 2);
  u16* dd1   = (u16*)alloc((size_t)Mp * 128 * 2);
  u16* dd2   = (u16*)alloc((size_t)Mp * 256 * 2);
  u16* dd3   = (u16*)alloc((size_t)Mp * 512 * 2);
  u16* xw    = (u16*)alloc((size_t)Mp * 512 * 2);
  u16* hb    = (u16*)alloc((size_t)Mp * 512 * 2);
  u16* emb   = (u16*)alloc((size_t)Mp * 512 * 2);
  u16* xw5   = (u16*)alloc((size_t)N * 20 * 2);
  u16* catT  = (u16*)alloc((size_t)1024 * Kx * 2);   // enc1T rows 0-511, W1T rows 512-1023
  u16* enc2T = (u16*)alloc((size_t)256 * 512 * 2);
  u16* enc3T = (u16*)alloc((size_t)128 * 256 * 2);
  u16* zlT   = (u16*)alloc((size_t)128 * 128 * 2);
  u16* dec1T = (u16*)alloc((size_t)128 * 128 * 2);
  u16* dec2T = (u16*)alloc((size_t)256 * 128 * 2);
  u16* dec3T = (u16*)alloc((size_t)512 * 256 * 2);
  u16* xbarT = (u16*)alloc((size_t)3072 * 512 * 2);
  u16* W2T   = (u16*)alloc((size_t)256 * 512 * 2);
  u16* W3T   = (u16*)alloc((size_t)128 * 256 * 2);
  u16* W4T   = (u16*)alloc((size_t)128 * 128 * 2);
  int* counts = (int*)alloc((size_t)N * 4);
  int* rowptr = (int*)alloc((size_t)(N + 1) * 4);
  int* cursor = (int*)alloc((size_t)N * 4);
  int* colss  = (int*)alloc((size_t)E * 4);
  float* valss = (float*)alloc((size_t)E * 4);

  // conversions
  convx_kernel<<<dim3(3, Mp), 256, 0, stream>>>(x, A0);
  auto convw = [&](const float* W, u16* Wt, int K, int Nw, int Kp, int Np) {
    convw_kernel<<<dim3((Kp + 255) / 256, Np), 256, 0, stream>>>(W, Wt, K, Nw, Kp);
  };
  convw(enc1_w, catT,             3000, 512, Kx, 512);
  convw(W1,     catT + 512 * Kx,  3000, 512, Kx, 512);
  convw(enc2_w, enc2T, 512, 256, 512, 256);
  convw(enc3_w, enc3T, 256, 128, 256, 128);
  convw(zl_w,   zlT,   128, 128, 128, 128);
  convw(dec1_w, dec1T, 128, 128, 128, 128);
  convw(dec2_w, dec2T, 128, 256, 128, 256);
  convw(dec3_w, dec3T, 256, 512, 256, 512);
  convw(xbar_w, xbarT, 512, 3000, 512, 3072);
  convw(W2,     W2T,   512, 256, 512, 256);
  convw(W3,     W3T,   256, 128, 256, 128);
  convw(W4,     W4T,   128, 128, 128, 128);

  // CSR build
  zero_kernel<<<(N + 255) / 256, 256, 0, stream>>>(counts, N);
  count_kernel<<<(E + 255) / 256, 256, 0, stream>>>(arows, counts, E);
  scan_kernel<<<1, 1024, 0, stream>>>(counts, rowptr, cursor, N);
  scatter_kernel<<<(E + 255) / 256, 256, 0, stream>>>(arows, acols, avals, cursor, colss, valss, E);

  const int MT = 313;    // ceil(40000/128)
  const int MT2 = 157;   // ceil(40000/256)
  // fused enc1 + W1 (256^2 deep-pipeline): A0 @ [enc1|W1] -> t1 (bias+relu) | xw (plain)
  gemm256<false, false, true, true><<<MT2 * 4, 512, 0, stream>>>(
      A0, Kx, catT, Kx, t1, xw, 512, enc1_b, N, 1024, Kx, MT2, 4);
  // rest of autoencoder
  gemm_bf16<true, true, true, 32><<<MT * 2, 256, 0, stream>>>(
      t1, 512, enc2T, 512, t2, 256, enc2_b, N, 256, 512, MT, 2);
  gemm_bf16<true, true, true, 32><<<MT * 1, 256, 0, stream>>>(
      t2, 256, enc3T, 256, t3, 128, enc3_b, N, 128, 256, MT, 1);
  gemm_bf16<true, false, true, 32><<<MT * 1, 256, 0, stream>>>(
      t3, 128, zlT, 128, zb, 128, zl_b, N, 128, 128, MT, 1);
  gemm_bf16<true, true, true, 32><<<MT * 1, 256, 0, stream>>>(
      zb, 128, dec1T, 128, dd1, 128, dec1_b, N, 128, 128, MT, 1);
  gemm_bf16<true, true, true, 32><<<MT * 2, 256, 0, stream>>>(
      dd1, 128, dec2T, 128, dd2, 256, dec2_b, N, 256, 128, MT, 2);
  // dec3 (256^2, N=512, K=256)
  gemm256<true, true, true, false><<<MT2 * 2, 512, 0, stream>>>(
      dd2, 256, dec3T, 256, dd3, nullptr, 512, dec3_b, N, 512, 256, MT2, 2);
  // xbar (256^2, fp32 out)
  gemm256<true, false, false, false><<<MT2 * 12, 512, 0, stream>>>(
      dd3, 512, xbarT, 512, out_xbar, nullptr, 3000, xbar_b, N, 3000, 512, MT2, 12);

  // GCN stack with attention-fused skips
  spmm_vec<512, true><<<N / 4, 256, 0, stream>>>(rowptr, colss, valss, xw, hb);
  attn_vec<512><<<N / 4, 256, 0, stream>>>(hb, t1, a1, emb);
  gemm_bf16<false, false, true, 32><<<MT * 2, 256, 0, stream>>>(
      emb, 512, W2T, 512, xw, 256, nullptr, N, 256, 512, MT, 2);
  spmm_vec<256, true><<<N / 4, 256, 0, stream>>>(rowptr, colss, valss, xw, hb);
  attn_vec<256><<<N / 4, 256, 0, stream>>>(hb, t2, a2, emb);
  gemm_bf16<false, false, true, 32><<<MT * 1, 256, 0, stream>>>(
      emb, 256, W3T, 256, xw, 128, nullptr, N, 128, 256, MT, 1);
  spmm_vec<128, true><<<N / 4, 256, 0, stream>>>(rowptr, colss, valss, xw, hb);
  attn_vec<128><<<N / 4, 256, 0, stream>>>(hb, t3, a3, emb);
  gemm_bf16<false, false, true, 32><<<MT * 1, 256, 0, stream>>>(
      emb, 128, W4T, 128, xw, 128, nullptr, N, 128, 128, MT, 1);
  spmm_vec<128, true><<<N / 4, 256, 0, stream>>>(rowptr, colss, valss, xw, hb);
  attn_vec<128><<<N / 4, 256, 0, stream>>>(hb, zb, a4, emb);

  // layer 5 (no relu) -> d_out
  xw5_kernel<<<N, 64, 0, stream>>>(emb, W5, xw5);
  spmm_out_kernel<<<N, 64, 0, stream>>>(rowptr, colss, valss, xw5, out_gcn);

  sig_exp_kernel<<<(G + 255) / 256, 256, 0, stream>>>(scale, additive, out_sig, out_exp, G);
}

// Round 6
// 1472.073 us; speedup vs baseline: 1.0284x; 1.0284x over previous
//
#include <hip/hip_runtime.h>
#include <cmath>

typedef unsigned short u16;
typedef unsigned int u32;
typedef __attribute__((ext_vector_type(8))) short short8;   // 8 x bf16 (4 VGPRs)
typedef __attribute__((ext_vector_type(4))) short short4v;  // 4 x bf16
typedef __attribute__((ext_vector_type(4))) float f32x4;

__device__ __forceinline__ float bf2f(u16 h) {
  union { u32 u; float f; } v; v.u = ((u32)h) << 16; return v.f;
}
__device__ __forceinline__ u16 f2bf(float f) {
  union { float f; u32 u; } v; v.f = f;
  u32 u = v.u;
  u32 r = (u + 0x7FFFu + ((u >> 16) & 1u)) >> 16;   // RNE
  return (u16)r;
}

// ---------------------------------------------------------------- conversions
__global__ void convx_kernel(const float* __restrict__ x, u16* __restrict__ A0) {
  int idx = blockIdx.x * 256 + threadIdx.x;   // short4 slot
  int r = blockIdx.y;
  if (idx >= 752) return;
  short4v o;
  if (r < 40000 && idx < 750) {
    float4 v = *(const float4*)(x + (size_t)r * 3000 + idx * 4);
    o[0] = (short)f2bf(v.x); o[1] = (short)f2bf(v.y);
    o[2] = (short)f2bf(v.z); o[3] = (short)f2bf(v.w);
  } else {
    o[0] = 0; o[1] = 0; o[2] = 0; o[3] = 0;
  }
  *(short4v*)(A0 + (size_t)r * 3008 + idx * 4) = o;
}

__global__ void convw_kernel(const float* __restrict__ W, u16* __restrict__ Wt,
                             int K, int N, int Kp) {
  int k = blockIdx.x * 256 + threadIdx.x;
  int n = blockIdx.y;
  if (k >= Kp) return;
  float v = (k < K && n < N) ? W[(size_t)k * N + n] : 0.f;
  Wt[(size_t)n * Kp + k] = f2bf(v);
}

// ---------------------------------------------------------------- CSR build
__global__ void zero_kernel(int* p, int n) {
  int i = blockIdx.x * 256 + threadIdx.x;
  if (i < n) p[i] = 0;
}
__global__ void count_kernel(const int* __restrict__ rows, int* __restrict__ counts, int E) {
  int i = blockIdx.x * 256 + threadIdx.x;
  if (i < E) atomicAdd(&counts[rows[i]], 1);
}
__global__ __launch_bounds__(1024) void scan_kernel(const int* __restrict__ counts,
                                                    int* __restrict__ rowptr,
                                                    int* __restrict__ cursor, int n) {
  __shared__ int buf[1024];
  __shared__ int carry_s;
  int tid = threadIdx.x;
  if (tid == 0) carry_s = 0;
  __syncthreads();
  for (int base = 0; base < n; base += 1024) {
    int i = base + tid;
    int v = (i < n) ? counts[i] : 0;
    buf[tid] = v;
    __syncthreads();
    for (int off = 1; off < 1024; off <<= 1) {
      int tv = (tid >= off) ? buf[tid - off] : 0;
      __syncthreads();
      buf[tid] += tv;
      __syncthreads();
    }
    int incl = buf[tid];
    int carry = carry_s;
    if (i < n) { int ex = carry + incl - v; rowptr[i] = ex; cursor[i] = ex; }
    __syncthreads();
    if (tid == 1023) carry_s = carry + incl;
    __syncthreads();
  }
  if (tid == 0) rowptr[n] = carry_s;
}
__global__ void scatter_kernel(const int* __restrict__ rows, const int* __restrict__ cols,
                               const float* __restrict__ vals, int* __restrict__ cursor,
                               int* __restrict__ cols_s, float* __restrict__ vals_s, int E) {
  int i = blockIdx.x * 256 + threadIdx.x;
  if (i < E) {
    int r = rows[i];
    int p = atomicAdd(&cursor[r], 1);
    cols_s[p] = cols[i];
    vals_s[p] = vals[i];
  }
}

// ---------------------------------------------------------------- 128x128 bf16 GEMM (small layers)
#define BM 128
#define BN 128
#define BK 32

template <bool BIAS, bool RELU, bool OUTBF16, int CH>
__global__ __launch_bounds__(256, 2) void gemm_bf16(
    const u16* __restrict__ A, int lda, const u16* __restrict__ Bt, int ldb,
    void* __restrict__ C1, int ldc,
    const float* __restrict__ bias, int M, int Nreal, int K, int MT, int NT) {
  __shared__ __align__(16) u16 As[2][BM * BK];
  __shared__ __align__(16) u16 Bs[2][BN * BK];
  const int lin = blockIdx.x;
  const int per = CH * NT;
  const int g = lin / per;
  const int r0 = lin - g * per;
  const int bx0 = g * CH;
  const int cw = min(CH, MT - bx0);
  const int bx = bx0 + r0 % cw;
  const int by = r0 / cw;

  const int tid = threadIdx.x;
  const int lane = tid & 63;
  const int wave = tid >> 6;
  const int mblk = bx * BM;
  const int nblk = by * BN;
  const int wm = (wave & 1) * 64;
  const int wn = (wave >> 1) * 64;
  const int ml = lane & 15;
  const int kg = lane >> 4;

  f32x4 acc[4][4];
#pragma unroll
  for (int i = 0; i < 4; ++i)
#pragma unroll
    for (int j = 0; j < 4; ++j) acc[i][j] = (f32x4)(0.f);

  const int nk = K / BK;
  const int sr = tid >> 2;
  const int sc = (tid & 3) * 8;
  const u16* gA0 = A + (size_t)(mblk + sr) * lda + sc;
  const u16* gA1 = A + (size_t)(mblk + sr + 64) * lda + sc;
  const u16* gB0 = Bt + (size_t)(nblk + sr) * ldb + sc;
  const u16* gB1 = Bt + (size_t)(nblk + sr + 64) * ldb + sc;

  auto stage = [&](int buf, int kt) {
    const int ko = kt * BK;
    u16* lA = &As[buf][0] + wave * 512;
    u16* lB = &Bs[buf][0] + wave * 512;
    __builtin_amdgcn_global_load_lds((const void*)(gA0 + ko), (void*)lA, 16, 0, 0);
    __builtin_amdgcn_global_load_lds((const void*)(gA1 + ko), (void*)(lA + 2048), 16, 0, 0);
    __builtin_amdgcn_global_load_lds((const void*)(gB0 + ko), (void*)lB, 16, 0, 0);
    __builtin_amdgcn_global_load_lds((const void*)(gB1 + ko), (void*)(lB + 2048), 16, 0, 0);
  };

  stage(0, 0);
  asm volatile("s_waitcnt vmcnt(0)" ::: "memory");
  __syncthreads();

  int cur = 0;
  for (int kt = 0; kt < nk; ++kt) {
    if (kt + 1 < nk) stage(cur ^ 1, kt + 1);
    short8 af[4], bfr[4];
#pragma unroll
    for (int i = 0; i < 4; ++i) {
      af[i] = *(const short8*)&As[cur][(wm + i * 16 + ml) * BK + kg * 8];
      bfr[i] = *(const short8*)&Bs[cur][(wn + i * 16 + ml) * BK + kg * 8];
    }
#pragma unroll
    for (int i = 0; i < 4; ++i)
#pragma unroll
      for (int j = 0; j < 4; ++j)
        acc[i][j] = __builtin_amdgcn_mfma_f32_16x16x32_bf16(af[i], bfr[j], acc[i][j], 0, 0, 0);
    asm volatile("s_waitcnt vmcnt(0)" ::: "memory");
    __syncthreads();
    cur ^= 1;
  }

#pragma unroll
  for (int i = 0; i < 4; ++i) {
    const int row0 = mblk + wm + i * 16 + kg * 4;
#pragma unroll
    for (int j = 0; j < 4; ++j) {
      const int col = nblk + wn + j * 16 + ml;
      if (col < Nreal) {
        float bv = BIAS ? bias[col] : 0.f;
#pragma unroll
        for (int r = 0; r < 4; ++r) {
          const int row = row0 + r;
          if (row < M) {
            float v = acc[i][j][r] + bv;
            if (RELU) v = fmaxf(v, 0.f);
            if (OUTBF16)
              ((u16*)C1)[(size_t)row * ldc + col] = f2bf(v);
            else
              ((float*)C1)[(size_t)row * ldc + col] = v;
          }
        }
      }
    }
  }
}

// ---------------------------------------------------------------- 256x256 8-wave GEMM
// BK=64, 2-deep LDS dbuf (128 KiB), chunk-XOR swizzle (0 bank conflicts, verified),
// ONE barrier per K-tile: stage kt+1 at tile top; fragment reads software-pipelined
// (quadrant q+1 A-frags loaded before quadrant q's MFMAs; compiler emits counted
// lgkmcnt), __syncthreads at tile end (its vmcnt(0) lands a full tile after the
// stage issues -> near-free). XCD-grouped block mapping (same-panel blocks -> same XCD).
template <bool BIAS, bool RELU, bool OUTBF16, bool SPLIT>
__global__ __launch_bounds__(512, 1) void gemm256(
    const u16* __restrict__ A, int lda, const u16* __restrict__ Bt, int ldb,
    void* __restrict__ C1, void* __restrict__ C2, int ldc,
    const float* __restrict__ bias, int M, int Nreal, int K, int MT2, int NT) {
  __shared__ __align__(16) u16 lds[2][2][256 * 64];
  const int tid = threadIdx.x;
  const int lane = tid & 63;
  const int wave = tid >> 6;
  const int wm = wave >> 2;        // 0..1
  const int wn = wave & 3;         // 0..3
  const int ml = lane & 15;
  const int kg = lane >> 4;

  // XCD-grouped mapping: ids in a group of 8*NT -> 8 A-panels; same-panel ids differ by 8
  const int grp = blockIdx.x / (8 * NT);
  const int rr = blockIdx.x % (8 * NT);
  const int nb = min(8, MT2 - grp * 8);
  const int bx = grp * 8 + rr % nb;
  const int by = rr / nb;
  const int mblk = bx * 256;
  const int nblk = by * 256;

  f32x4 acc[8][4];
#pragma unroll
  for (int i = 0; i < 8; ++i)
#pragma unroll
    for (int j = 0; j < 4; ++j) acc[i][j] = (f32x4)(0.f);

  // staging: one gload_lds per wave = 64 lanes x 16 B = 1 KB; 8 waves cover 64 rows.
  // LDS phys chunk c of row r holds logical chunk c ^ (r&7) (XOR involution, both sides).
  const int srow = tid >> 3;
  const int clog = (tid & 7) ^ (srow & 7);
  const size_t abase = (size_t)(mblk + srow) * lda + clog * 8;
  const size_t bbase = (size_t)(nblk + srow) * ldb + clog * 8;
  const int NKT = K / 64;

  auto stageA = [&](int d, int kt, int h) {
    u16* dst = &lds[d][0][0] + h * 4096 + wave * 512;
    const u16* src = A + abase + (size_t)h * 64 * lda + kt * 64;
    __builtin_amdgcn_global_load_lds((const void*)src, (void*)dst, 16, 0, 0);
  };
  auto stageB = [&](int d, int kt, int h) {
    u16* dst = &lds[d][1][0] + h * 4096 + wave * 512;
    const u16* src = Bt + bbase + (size_t)h * 64 * ldb + kt * 64;
    __builtin_amdgcn_global_load_lds((const void*)src, (void*)dst, 16, 0, 0);
  };
  auto stageAll = [&](int d, int kt) {
    stageB(d, kt, 0); stageB(d, kt, 1); stageB(d, kt, 2); stageB(d, kt, 3);
    stageA(d, kt, 0); stageA(d, kt, 1); stageA(d, kt, 2); stageA(d, kt, 3);
  };
  auto readA = [&](int d, int im, int kk) -> short8 {
    const int r = wm * 128 + im * 16 + ml;
    const int ch = (kk * 4 + kg) ^ (r & 7);
    return *(const short8*)&lds[d][0][r * 64 + ch * 8];
  };
  auto readB = [&](int d, int j, int kk) -> short8 {
    const int r = wn * 64 + j * 16 + ml;
    const int ch = (kk * 4 + kg) ^ (r & 7);
    return *(const short8*)&lds[d][1][r * 64 + ch * 8];
  };

  // prologue: stage tile 0; __syncthreads drains vmcnt and fences LDS
  stageAll(0, 0);
  __syncthreads();

  for (int kt = 0; kt < NKT; ++kt) {
    const int d = kt & 1;
    if (kt + 1 < NKT) stageAll(d ^ 1, kt + 1);   // issue early; drained by tile-end sync

    // B fragments for the whole tile (8 reads, live across all quadrants)
    short8 b[4][2];
#pragma unroll
    for (int j = 0; j < 4; ++j) { b[j][0] = readB(d, j, 0); b[j][1] = readB(d, j, 1); }
    // A-quadrant register pipeline: read q+1 before MFMA q (compiler counted-lgkmcnt)
    short8 aC0k0 = readA(d, 0, 0), aC0k1 = readA(d, 0, 1);
    short8 aC1k0 = readA(d, 1, 0), aC1k1 = readA(d, 1, 1);
#pragma unroll
    for (int q = 0; q < 4; ++q) {
      short8 aN0k0, aN0k1, aN1k0, aN1k1;
      if (q < 3) {
        aN0k0 = readA(d, 2 * (q + 1), 0);     aN0k1 = readA(d, 2 * (q + 1), 1);
        aN1k0 = readA(d, 2 * (q + 1) + 1, 0); aN1k1 = readA(d, 2 * (q + 1) + 1, 1);
      }
      __builtin_amdgcn_s_setprio(1);
#pragma unroll
      for (int j = 0; j < 4; ++j) {
        acc[2 * q][j]     = __builtin_amdgcn_mfma_f32_16x16x32_bf16(aC0k0, b[j][0], acc[2 * q][j], 0, 0, 0);
        acc[2 * q + 1][j] = __builtin_amdgcn_mfma_f32_16x16x32_bf16(aC1k0, b[j][0], acc[2 * q + 1][j], 0, 0, 0);
      }
#pragma unroll
      for (int j = 0; j < 4; ++j) {
        acc[2 * q][j]     = __builtin_amdgcn_mfma_f32_16x16x32_bf16(aC0k1, b[j][1], acc[2 * q][j], 0, 0, 0);
        acc[2 * q + 1][j] = __builtin_amdgcn_mfma_f32_16x16x32_bf16(aC1k1, b[j][1], acc[2 * q + 1][j], 0, 0, 0);
      }
      __builtin_amdgcn_s_setprio(0);
      if (q < 3) { aC0k0 = aN0k0; aC0k1 = aN0k1; aC1k0 = aN1k0; aC1k1 = aN1k1; }
    }
    __syncthreads();   // vmcnt(0) for kt+1 stage (issued ~full tile ago) + LDS fence
  }

  // epilogue
  const int crow0 = mblk + wm * 128;
  const int ccol0 = nblk + wn * 64;
#pragma unroll
  for (int i = 0; i < 8; ++i) {
    const int row0 = crow0 + i * 16 + kg * 4;
#pragma unroll
    for (int j = 0; j < 4; ++j) {
      const int col = ccol0 + j * 16 + ml;
      if (SPLIT) {
        const bool second = (nblk >= 512);
        const float bv = second ? 0.f : bias[col];
#pragma unroll
        for (int r = 0; r < 4; ++r) {
          const int row = row0 + r;
          if (row < M) {
            float v = acc[i][j][r] + bv;
            if (!second) v = fmaxf(v, 0.f);
            u16* dst = second ? (u16*)C2 : (u16*)C1;
            dst[(size_t)row * 512 + (second ? col - 512 : col)] = f2bf(v);
          }
        }
      } else if (col < Nreal) {
        const float bv = BIAS ? bias[col] : 0.f;
#pragma unroll
        for (int r = 0; r < 4; ++r) {
          const int row = row0 + r;
          if (row < M) {
            float v = acc[i][j][r] + bv;
            if (RELU) v = fmaxf(v, 0.f);
            if (OUTBF16)
              ((u16*)C1)[(size_t)row * ldc + col] = f2bf(v);
            else
              ((float*)C1)[(size_t)row * ldc + col] = v;
          }
        }
      }
    }
  }
}

// ---------------------------------------------------------------- SpMM (CSR), vectorized
template <int D, bool RELU>
__global__ __launch_bounds__(256) void spmm_vec(const int* __restrict__ rowptr,
                                                const int* __restrict__ colidx,
                                                const float* __restrict__ vals,
                                                const u16* __restrict__ X,
                                                u16* __restrict__ Y) {
  constexpr int VE = D / 64;
  const int wave = threadIdx.x >> 6, lane = threadIdx.x & 63;
  const int row = blockIdx.x * 4 + wave;
  const int co = lane * VE;
  float acc[VE];
#pragma unroll
  for (int j = 0; j < VE; ++j) acc[j] = 0.f;
  const int s = rowptr[row], e = rowptr[row + 1];
  for (int i = s; i < e; ++i) {
    const int c = colidx[i];
    const float v = vals[i];
    const u16* xr = X + (size_t)c * D + co;
    if constexpr (VE == 8) {
      short8 x8 = *(const short8*)xr;
#pragma unroll
      for (int j = 0; j < 8; ++j) acc[j] += v * bf2f((u16)x8[j]);
    } else if constexpr (VE == 4) {
      short4v x4 = *(const short4v*)xr;
#pragma unroll
      for (int j = 0; j < 4; ++j) acc[j] += v * bf2f((u16)x4[j]);
    } else {
      u32 x2 = *(const u32*)xr;
      acc[0] += v * bf2f((u16)(x2 & 0xffffu));
      acc[1] += v * bf2f((u16)(x2 >> 16));
    }
  }
  u16* yr = Y + (size_t)row * D + co;
  if constexpr (VE == 8) {
    short8 o;
#pragma unroll
    for (int j = 0; j < 8; ++j) { float f = RELU ? fmaxf(acc[j], 0.f) : acc[j]; o[j] = (short)f2bf(f); }
    *(short8*)yr = o;
  } else if constexpr (VE == 4) {
    short4v o;
#pragma unroll
    for (int j = 0; j < 4; ++j) { float f = RELU ? fmaxf(acc[j], 0.f) : acc[j]; o[j] = (short)f2bf(f); }
    *(short4v*)yr = o;
  } else {
    float f0 = RELU ? fmaxf(acc[0], 0.f) : acc[0];
    float f1 = RELU ? fmaxf(acc[1], 0.f) : acc[1];
    *(u32*)yr = (u32)f2bf(f0) | ((u32)f2bf(f1) << 16);
  }
}

// final layer: D=20, fp32 out, no relu
__global__ __launch_bounds__(64) void spmm_out_kernel(const int* __restrict__ rowptr,
                                                      const int* __restrict__ colidx,
                                                      const float* __restrict__ vals,
                                                      const u16* __restrict__ X,
                                                      float* __restrict__ Y) {
  int row = blockIdx.x;
  int c = threadIdx.x;
  float acc = 0.f;
  int s = rowptr[row], e = rowptr[row + 1];
  for (int i = s; i < e; ++i) {
    int col = colidx[i];
    float v = vals[i];
    if (c < 20) acc += v * bf2f(X[(size_t)col * 20 + c]);
  }
  if (c < 20) Y[(size_t)row * 20 + c] = acc;
}

// ---------------------------------------------------------------- attention gate (vectorized)
template <int D>
__global__ __launch_bounds__(256) void attn_vec(const u16* __restrict__ h,
                                                const u16* __restrict__ t,
                                                const float* __restrict__ a,
                                                u16* __restrict__ emb) {
  constexpr int VE = D / 64;
  const int wave = threadIdx.x >> 6, lane = threadIdx.x & 63;
  const int row = blockIdx.x * 4 + wave;
  const int co = lane * VE;
  const u16* hr = h + (size_t)row * D + co;
  const u16* tr = t + (size_t)row * D + co;
  float hv[VE], tv[VE];
  if constexpr (VE == 8) {
    short8 h8 = *(const short8*)hr, t8 = *(const short8*)tr;
#pragma unroll
    for (int j = 0; j < 8; ++j) { hv[j] = bf2f((u16)h8[j]); tv[j] = bf2f((u16)t8[j]); }
  } else if constexpr (VE == 4) {
    short4v h4 = *(const short4v*)hr, t4 = *(const short4v*)tr;
#pragma unroll
    for (int j = 0; j < 4; ++j) { hv[j] = bf2f((u16)h4[j]); tv[j] = bf2f((u16)t4[j]); }
  } else {
    u32 h2 = *(const u32*)hr, t2 = *(const u32*)tr;
    hv[0] = bf2f((u16)(h2 & 0xffffu)); hv[1] = bf2f((u16)(h2 >> 16));
    tv[0] = bf2f((u16)(t2 & 0xffffu)); tv[1] = bf2f((u16)(t2 >> 16));
  }
  float wh = 0.f, wt = 0.f;
#pragma unroll
  for (int j = 0; j < VE; ++j) {
    float av = a[co + j];
    wh += av * hv[j];
    wt += av * tv[j];
  }
  for (int off = 32; off; off >>= 1) {
    wh += __shfl_xor(wh, off);
    wt += __shfl_xor(wt, off);
  }
  float m = fmaxf(wh, wt);
  float e1 = expf(wh - m), e2 = expf(wt - m);
  float inv = 1.f / (e1 + e2);
  float b1 = e1 * inv, b2 = e2 * inv;
  u16* er = emb + (size_t)row * D + co;
  if constexpr (VE == 8) {
    short8 o;
#pragma unroll
    for (int j = 0; j < 8; ++j) o[j] = (short)f2bf(b1 * hv[j] + b2 * tv[j]);
    *(short8*)er = o;
  } else if constexpr (VE == 4) {
    short4v o;
#pragma unroll
    for (int j = 0; j < 4; ++j) o[j] = (short)f2bf(b1 * hv[j] + b2 * tv[j]);
    *(short4v*)er = o;
  } else {
    *(u32*)er = (u32)f2bf(b1 * hv[0] + b2 * tv[0]) | ((u32)f2bf(b1 * hv[1] + b2 * tv[1]) << 16);
  }
}

// emb4[40000,128] @ W5[128,20] -> xw5 bf16 [40000,20]
__global__ __launch_bounds__(64) void xw5_kernel(const u16* __restrict__ emb,
                                                 const float* __restrict__ W5,
                                                 u16* __restrict__ xw5) {
  int row = blockIdx.x;
  int c = threadIdx.x;
  if (c >= 20) return;
  const short8* er = (const short8*)(emb + (size_t)row * 128);
  float acc = 0.f;
#pragma unroll
  for (int k8 = 0; k8 < 16; ++k8) {
    short8 v = er[k8];
#pragma unroll
    for (int j = 0; j < 8; ++j) acc += bf2f((u16)v[j]) * W5[(k8 * 8 + j) * 20 + c];
  }
  xw5[(size_t)row * 20 + c] = f2bf(acc);
}

__global__ void sig_exp_kernel(const float* __restrict__ scale, const float* __restrict__ additive,
                               float* __restrict__ osig, float* __restrict__ oexp, int g) {
  int i = blockIdx.x * 256 + threadIdx.x;
  if (i < g) {
    osig[i] = 1.f / (1.f + expf(-scale[i]));
    oexp[i] = expf(additive[i]);
  }
}

// ---------------------------------------------------------------- launch
extern "C" void kernel_launch(void* const* d_in, const int* in_sizes, int n_in,
                              void* d_out, int out_size, void* d_ws, size_t ws_size,
                              hipStream_t stream) {
  (void)n_in; (void)out_size; (void)ws_size;
  const float* x      = (const float*)d_in[0];
  const int*   arows  = (const int*)d_in[1];
  const int*   acols  = (const int*)d_in[2];
  const float* avals  = (const float*)d_in[3];
  const float* W1     = (const float*)d_in[4];
  const float* W2     = (const float*)d_in[5];
  const float* W3     = (const float*)d_in[6];
  const float* W4     = (const float*)d_in[7];
  const float* W5     = (const float*)d_in[8];
  const float* enc1_w = (const float*)d_in[9],  *enc1_b = (const float*)d_in[10];
  const float* enc2_w = (const float*)d_in[11], *enc2_b = (const float*)d_in[12];
  const float* enc3_w = (const float*)d_in[13], *enc3_b = (const float*)d_in[14];
  const float* zl_w   = (const float*)d_in[15], *zl_b   = (const float*)d_in[16];
  const float* dec1_w = (const float*)d_in[17], *dec1_b = (const float*)d_in[18];
  const float* dec2_w = (const float*)d_in[19], *dec2_b = (const float*)d_in[20];
  const float* dec3_w = (const float*)d_in[21], *dec3_b = (const float*)d_in[22];
  const float* xbar_w = (const float*)d_in[23], *xbar_b = (const float*)d_in[24];
  const float* a1 = (const float*)d_in[25], *a2 = (const float*)d_in[26];
  const float* a3 = (const float*)d_in[27], *a4 = (const float*)d_in[28];
  const float* scale = (const float*)d_in[29], *additive = (const float*)d_in[30];

  const int E = in_sizes[1];
  const int N = 40000, G = 3000, Kx = 3008;
  const int Mp = 40192;          // 157 * 256

  float* out      = (float*)d_out;
  float* out_gcn  = out;                                   // [40000,20]
  float* out_xbar = out + (size_t)N * 20;                  // [40000,3000]
  float* out_sig  = out_xbar + (size_t)N * G;              // [3000]
  float* out_exp  = out_sig + G;                           // [3000]

  char* wsb = (char*)d_ws;
  size_t off = 0;
  auto alloc = [&](size_t b) -> void* {
    void* p = wsb + off;
    off = (off + b + 255) & ~(size_t)255;
    return p;
  };
  u16* A0    = (u16*)alloc((size_t)Mp * Kx * 2);
  u16* t1    = (u16*)alloc((size_t)Mp * 512 * 2);
  u16* t2    = (u16*)alloc((size_t)Mp * 256 * 2);
  u16* t3    = (u16*)alloc((size_t)Mp * 128 * 2);
  u16* zb    = (u16*)alloc((size_t)Mp * 128 * 2);
  u16* dd1   = (u16*)alloc((size_t)Mp * 128 * 2);
  u16* dd2   = (u16*)alloc((size_t)Mp * 256 * 2);
  u16* dd3   = (u16*)alloc((size_t)Mp * 512 * 2);
  u16* xw    = (u16*)alloc((size_t)Mp * 512 * 2);
  u16* hb    = (u16*)alloc((size_t)Mp * 512 * 2);
  u16* emb   = (u16*)alloc((size_t)Mp * 512 * 2);
  u16* xw5   = (u16*)alloc((size_t)N * 20 * 2);
  u16* catT  = (u16*)alloc((size_t)1024 * Kx * 2);   // enc1T rows 0-511, W1T rows 512-1023
  u16* enc2T = (u16*)alloc((size_t)256 * 512 * 2);
  u16* enc3T = (u16*)alloc((size_t)128 * 256 * 2);
  u16* zlT   = (u16*)alloc((size_t)128 * 128 * 2);
  u16* dec1T = (u16*)alloc((size_t)128 * 128 * 2);
  u16* dec2T = (u16*)alloc((size_t)256 * 128 * 2);
  u16* dec3T = (u16*)alloc((size_t)512 * 256 * 2);
  u16* xbarT = (u16*)alloc((size_t)3072 * 512 * 2);
  u16* W2T   = (u16*)alloc((size_t)256 * 512 * 2);
  u16* W3T   = (u16*)alloc((size_t)128 * 256 * 2);
  u16* W4T   = (u16*)alloc((size_t)128 * 128 * 2);
  int* counts = (int*)alloc((size_t)N * 4);
  int* rowptr = (int*)alloc((size_t)(N + 1) * 4);
  int* cursor = (int*)alloc((size_t)N * 4);
  int* colss  = (int*)alloc((size_t)E * 4);
  float* valss = (float*)alloc((size_t)E * 4);

  // conversions
  convx_kernel<<<dim3(3, Mp), 256, 0, stream>>>(x, A0);
  auto convw = [&](const float* W, u16* Wt, int K, int Nw, int Kp, int Np) {
    convw_kernel<<<dim3((Kp + 255) / 256, Np), 256, 0, stream>>>(W, Wt, K, Nw, Kp);
  };
  convw(enc1_w, catT,             3000, 512, Kx, 512);
  convw(W1,     catT + 512 * Kx,  3000, 512, Kx, 512);
  convw(enc2_w, enc2T, 512, 256, 512, 256);
  convw(enc3_w, enc3T, 256, 128, 256, 128);
  convw(zl_w,   zlT,   128, 128, 128, 128);
  convw(dec1_w, dec1T, 128, 128, 128, 128);
  convw(dec2_w, dec2T, 128, 256, 128, 256);
  convw(dec3_w, dec3T, 256, 512, 256, 512);
  convw(xbar_w, xbarT, 512, 3000, 512, 3072);
  convw(W2,     W2T,   512, 256, 512, 256);
  convw(W3,     W3T,   256, 128, 256, 128);
  convw(W4,     W4T,   128, 128, 128, 128);

  // CSR build
  zero_kernel<<<(N + 255) / 256, 256, 0, stream>>>(counts, N);
  count_kernel<<<(E + 255) / 256, 256, 0, stream>>>(arows, counts, E);
  scan_kernel<<<1, 1024, 0, stream>>>(counts, rowptr, cursor, N);
  scatter_kernel<<<(E + 255) / 256, 256, 0, stream>>>(arows, acols, avals, cursor, colss, valss, E);

  const int MT = 313;    // ceil(40000/128)
  const int MT2 = 157;   // ceil(40000/256)
  // fused enc1 + W1 (256^2): A0 @ [enc1|W1] -> t1 (bias+relu) | xw (plain)
  gemm256<false, false, true, true><<<MT2 * 4, 512, 0, stream>>>(
      A0, Kx, catT, Kx, t1, xw, 512, enc1_b, N, 1024, Kx, MT2, 4);
  // rest of autoencoder
  gemm_bf16<true, true, true, 32><<<MT * 2, 256, 0, stream>>>(
      t1, 512, enc2T, 512, t2, 256, enc2_b, N, 256, 512, MT, 2);
  gemm_bf16<true, true, true, 32><<<MT * 1, 256, 0, stream>>>(
      t2, 256, enc3T, 256, t3, 128, enc3_b, N, 128, 256, MT, 1);
  gemm_bf16<true, false, true, 32><<<MT * 1, 256, 0, stream>>>(
      t3, 128, zlT, 128, zb, 128, zl_b, N, 128, 128, MT, 1);
  gemm_bf16<true, true, true, 32><<<MT * 1, 256, 0, stream>>>(
      zb, 128, dec1T, 128, dd1, 128, dec1_b, N, 128, 128, MT, 1);
  gemm_bf16<true, true, true, 32><<<MT * 2, 256, 0, stream>>>(
      dd1, 128, dec2T, 128, dd2, 256, dec2_b, N, 256, 128, MT, 2);
  // dec3 (256^2, N=512, K=256)
  gemm256<true, true, true, false><<<MT2 * 2, 512, 0, stream>>>(
      dd2, 256, dec3T, 256, dd3, nullptr, 512, dec3_b, N, 512, 256, MT2, 2);
  // xbar (256^2, fp32 out)
  gemm256<true, false, false, false><<<MT2 * 12, 512, 0, stream>>>(
      dd3, 512, xbarT, 512, out_xbar, nullptr, 3000, xbar_b, N, 3000, 512, MT2, 12);

  // GCN stack with attention-fused skips
  spmm_vec<512, true><<<N / 4, 256, 0, stream>>>(rowptr, colss, valss, xw, hb);
  attn_vec<512><<<N / 4, 256, 0, stream>>>(hb, t1, a1, emb);
  gemm_bf16<false, false, true, 32><<<MT * 2, 256, 0, stream>>>(
      emb, 512, W2T, 512, xw, 256, nullptr, N, 256, 512, MT, 2);
  spmm_vec<256, true><<<N / 4, 256, 0, stream>>>(rowptr, colss, valss, xw, hb);
  attn_vec<256><<<N / 4, 256, 0, stream>>>(hb, t2, a2, emb);
  gemm_bf16<false, false, true, 32><<<MT * 1, 256, 0, stream>>>(
      emb, 256, W3T, 256, xw, 128, nullptr, N, 128, 256, MT, 1);
  spmm_vec<128, true><<<N / 4, 256, 0, stream>>>(rowptr, colss, valss, xw, hb);
  attn_vec<128><<<N / 4, 256, 0, stream>>>(hb, t3, a3, emb);
  gemm_bf16<false, false, true, 32><<<MT * 1, 256, 0, stream>>>(
      emb, 128, W4T, 128, xw, 128, nullptr, N, 128, 128, MT, 1);
  spmm_vec<128, true><<<N / 4, 256, 0, stream>>>(rowptr, colss, valss, xw, hb);
  attn_vec<128><<<N / 4, 256, 0, stream>>>(hb, zb, a4, emb);

  // layer 5 (no relu) -> d_out
  xw5_kernel<<<N, 64, 0, stream>>>(emb, W5, xw5);
  spmm_out_kernel<<<N, 64, 0, stream>>>(rowptr, colss, valss, xw5, out_gcn);

  sig_exp_kernel<<<(G + 255) / 256, 256, 0, stream>>>(scale, additive, out_sig, out_exp, G);
}